// Round 3
// baseline (305.881 us; speedup 1.0000x reference)
//
#include <hip/hip_runtime.h>
#include <math.h>

#define N_IMG 6
#define CIN   256
#define H_IN  32
#define W_IN  88
#define SP    2816      // 32*88
#define HH    34        // H+2 halo
#define WW    90        // W+2 halo
#define SPH   3060      // 34*90
#define COUTC 80
#define EPSBN 1e-5f

typedef _Float16 half8 __attribute__((ext_vector_type(8)));
typedef _Float16 half2v __attribute__((ext_vector_type(2)));
typedef float floatx4 __attribute__((ext_vector_type(4)));

// ---------------- weight prep ----------------
// w (OIHW [256][256][3][3]) -> fp16 [oc][tap][ic], coalesced via LDS
__global__ __launch_bounds__(256) void prep_w33(const float* __restrict__ w,
                                                _Float16* __restrict__ wT) {
  __shared__ float s[2304];
  const int oc = blockIdx.x;
  const int tid = threadIdx.x;
  const float* wo = w + (size_t)oc * 2304;
  for (int i = tid; i < 2304; i += 256) s[i] = wo[i];
  __syncthreads();
  for (int i = tid; i < 2304; i += 256) {
    const int tap = i >> 8;
    const int ic  = i & 255;
    wT[(size_t)oc * 2304 + i] = (_Float16)s[ic * 9 + tap];
  }
}

// w3 [80][256] -> fp16 (plain cast copy, [oc][ic])
__global__ __launch_bounds__(256) void prep_w11(const float* __restrict__ w,
                                                _Float16* __restrict__ wT) {
  int idx = blockIdx.x * 256 + threadIdx.x;
  if (idx >= CIN * COUTC) return;
  wT[idx] = (_Float16)w[idx];
}

// img fp32 NCHW -> fp16 NHWC with zero halo ([im][34][90][256])
__global__ __launch_bounds__(256) void nchw_to_nhwc(const float* __restrict__ img,
                                                    _Float16* __restrict__ x0) {
  __shared__ float t[64][65];
  const int sp0 = blockIdx.x * 64;
  const int ic0 = blockIdx.y * 64;
  const int im  = blockIdx.z;
  const int tx = threadIdx.x & 63;
  const int ty = threadIdx.x >> 6;   // 0..3
  for (int r = ty; r < 64; r += 4)
    t[r][tx] = img[((size_t)(im * CIN + ic0 + r)) * SP + sp0 + tx];
  __syncthreads();
  for (int r = ty; r < 64; r += 4) {
    const int sp = sp0 + r;
    const int h = sp / 88;
    const int w = sp - h * 88;
    x0[((size_t)im * SPH + h * WW + w + WW + 1) * CIN + ic0 + tx] = (_Float16)t[tx][r];
  }
}

// ---------------- 3x3 conv + BN + ReLU, fp16 MFMA implicit GEMM ----------------
// tile 128(M) x 64(N), 4 waves as 2Mx2N (wave 64x32), BK=64.
// A: global_load_lds into XOR-swizzled LDS (swizzle on global src addr).
// B: direct global->register (L2-resident weights).
__global__ __launch_bounds__(256) void conv3x3_mfma(
    const _Float16* __restrict__ x, const _Float16* __restrict__ wT,
    const float* __restrict__ bias, const float* __restrict__ gamma,
    const float* __restrict__ beta, const float* __restrict__ bnm,
    const float* __restrict__ bnv, _Float16* __restrict__ out,
    int OW, int OB, int imStride)
{
  __shared__ _Float16 As[128 * 64];   // [row][granule^ (row&7)][8]

  const int tid = threadIdx.x;
  const int m0 = blockIdx.x * 128;
  const int n0 = blockIdx.y * 64;
  const int im = blockIdx.z;
  const _Float16* xim = x + (size_t)im * SPH * CIN;

  // staging source offsets (halo coords + XOR granule swizzle)
  int sBase[4];
  #pragma unroll
  for (int i = 0; i < 4; ++i) {
    const int c = tid + i * 256;
    const int row = c >> 3;
    const int m = m0 + row;
    const int h = m / 88;
    const int w = m - h * 88;
    sBase[i] = ((h + 1) * WW + (w + 1)) * CIN + (((c & 7) ^ (row & 7)) * 8);
  }

  const int wv   = tid >> 6;
  const int lane = tid & 63;
  const int fr   = lane & 15;
  const int q    = lane >> 4;
  const int q8   = q * 8;
  const int q4   = q * 4;
  const int mw   = (wv & 1) * 64;
  const int nw   = (wv >> 1) * 32;
  const int fr7  = fr & 7;

  const _Float16* wrow0 = wT + (size_t)(n0 + nw + fr) * 2304 + q8;
  const _Float16* wrow1 = wT + (size_t)(n0 + nw + 16 + fr) * 2304 + q8;

  floatx4 acc[4][2];
  #pragma unroll
  for (int i = 0; i < 4; ++i)
    #pragma unroll
    for (int j = 0; j < 2; ++j) {
      acc[i][j][0] = 0.f; acc[i][j][1] = 0.f; acc[i][j][2] = 0.f; acc[i][j][3] = 0.f;
    }

  for (int tap = 0; tap < 9; ++tap) {
    const int dy = tap / 3 - 1;
    const int dx = tap - (tap / 3) * 3 - 1;
    const int dtap = (dy * WW + dx) * CIN;

    #pragma unroll
    for (int icc = 0; icc < 256; icc += 64) {
      const int woff = tap * 256 + icc;
      // B fragments: direct from global (L2-hot), issued early
      half8 bf00 = *(const half8*)(wrow0 + woff);
      half8 bf01 = *(const half8*)(wrow0 + woff + 32);
      half8 bf10 = *(const half8*)(wrow1 + woff);
      half8 bf11 = *(const half8*)(wrow1 + woff + 32);
      // A tile: async DMA global->LDS, 16B/lane, lane-linear dest
      #pragma unroll
      for (int i = 0; i < 4; ++i) {
        __builtin_amdgcn_global_load_lds(
            (const __attribute__((address_space(1))) void*)(xim + sBase[i] + dtap + icc),
            (__attribute__((address_space(3))) void*)(&As[(wv * 64 + i * 256) * 8]),
            16, 0, 0);
      }
      __syncthreads();

      #pragma unroll
      for (int ks = 0; ks < 2; ++ks) {
        half8 af[4];
        #pragma unroll
        for (int i = 0; i < 4; ++i) {
          const int row = mw + i * 16 + fr;
          const int phys = (ks * 4 + q) ^ fr7;
          af[i] = *(const half8*)(&As[row * 64 + phys * 8]);
        }
        const half8 b0 = ks ? bf01 : bf00;
        const half8 b1 = ks ? bf11 : bf10;
        #pragma unroll
        for (int i = 0; i < 4; ++i) {
          acc[i][0] = __builtin_amdgcn_mfma_f32_16x16x32_f16(af[i], b0, acc[i][0], 0, 0, 0);
          acc[i][1] = __builtin_amdgcn_mfma_f32_16x16x32_f16(af[i], b1, acc[i][1], 0, 0, 0);
        }
      }
      __syncthreads();
    }
  }

  // epilogue: BN + ReLU, store fp16 NHWC (halo or flat per OW/OB/imStride)
  #pragma unroll
  for (int j = 0; j < 2; ++j) {
    const int oc = n0 + nw + j * 16 + fr;
    const float sc = gamma[oc] * rsqrtf(bnv[oc] + EPSBN);
    const float sh = (bias[oc] - bnm[oc]) * sc + beta[oc];
    #pragma unroll
    for (int i = 0; i < 4; ++i) {
      #pragma unroll
      for (int r = 0; r < 4; ++r) {
        const int m = m0 + mw + i * 16 + q4 + r;
        const int h = m / 88;
        const int w = m - h * 88;
        const float v = fmaxf(fmaf(acc[i][j][r], sc, sh), 0.f);
        out[((size_t)im * imStride + h * OW + w + OB) * CIN + oc] = (_Float16)v;
      }
    }
  }
}

// ---------------- 1x1 conv (256->80) + bias, fp16 MFMA, NHWC fp16 out ----------------
__global__ __launch_bounds__(256) void conv1x1_mfma(
    const _Float16* __restrict__ x, const _Float16* __restrict__ wT,
    const float* __restrict__ bias, _Float16* __restrict__ feat)
{
  __shared__ _Float16 As[128 * 72];
  __shared__ _Float16 Bs[80 * 72];

  const int tid = threadIdx.x;
  const int m0 = blockIdx.x * 128;

  int rr[4], kk4[4];
  #pragma unroll
  for (int i = 0; i < 4; ++i) {
    const int c = tid + 256 * i;
    rr[i]  = c >> 3;
    kk4[i] = (c & 7) * 8;
  }
  const int rB0 = tid >> 3,         kB0 = (tid & 7) * 8;
  const int rB1 = (tid + 256) >> 3, kB1 = kB0;
  const int rB2 = (tid + 512) >> 3, kB2 = kB0;

  const int lane = tid & 63;
  const int wv = tid >> 6;
  const int mw = wv * 32;
  const int fr = lane & 15;
  const int q8 = (lane >> 4) * 8;
  const int q4 = (lane >> 4) * 4;

  floatx4 acc[2][5];
  #pragma unroll
  for (int i = 0; i < 2; ++i)
    #pragma unroll
    for (int j = 0; j < 5; ++j) {
      acc[i][j][0] = 0.f; acc[i][j][1] = 0.f; acc[i][j][2] = 0.f; acc[i][j][3] = 0.f;
    }

  for (int icc = 0; icc < 256; icc += 64) {
    half8 av[4];
    #pragma unroll
    for (int i = 0; i < 4; ++i)
      av[i] = *(const half8*)(x + (size_t)(m0 + rr[i]) * CIN + icc + kk4[i]);
    half8 b0 = *(const half8*)(wT + (size_t)rB0 * CIN + icc + kB0);
    half8 b1 = *(const half8*)(wT + (size_t)rB1 * CIN + icc + kB1);
    half8 b2 = {};
    if (tid < 128) b2 = *(const half8*)(wT + (size_t)rB2 * CIN + icc + kB2);

    #pragma unroll
    for (int i = 0; i < 4; ++i)
      *(half8*)(&As[rr[i] * 72 + kk4[i]]) = av[i];
    *(half8*)(&Bs[rB0 * 72 + kB0]) = b0;
    *(half8*)(&Bs[rB1 * 72 + kB1]) = b1;
    if (tid < 128) *(half8*)(&Bs[rB2 * 72 + kB2]) = b2;
    __syncthreads();

    const _Float16* Ab = &As[(mw + fr) * 72 + q8];
    const _Float16* Bb = &Bs[fr * 72 + q8];
    #pragma unroll
    for (int ks = 0; ks < 2; ++ks) {
      half8 af[2], bfv[5];
      #pragma unroll
      for (int i = 0; i < 2; ++i) af[i] = *(const half8*)(Ab + i * (16 * 72) + ks * 32);
      #pragma unroll
      for (int j = 0; j < 5; ++j) bfv[j] = *(const half8*)(Bb + j * (16 * 72) + ks * 32);
      #pragma unroll
      for (int i = 0; i < 2; ++i)
        #pragma unroll
        for (int j = 0; j < 5; ++j)
          acc[i][j] = __builtin_amdgcn_mfma_f32_16x16x32_f16(af[i], bfv[j], acc[i][j], 0, 0, 0);
    }
    __syncthreads();
  }

  #pragma unroll
  for (int j = 0; j < 5; ++j) {
    const int oc = j * 16 + fr;
    const float bb = bias[oc];
    #pragma unroll
    for (int i = 0; i < 2; ++i) {
      const int mbase = m0 + mw + i * 16 + q4;
      #pragma unroll
      for (int r = 0; r < 4; ++r)
        feat[(size_t)(mbase + r) * COUTC + oc] = (_Float16)(acc[i][j][r] + bb);
    }
  }
}

// ---------------- projection + bilinear + max over cams + mean over z ----------------
// block: 320 threads = 8 cells x 40 channel-pairs. feat fp16 NHWC.
__global__ __launch_bounds__(320) void bev_sample(
    const _Float16* __restrict__ feat, const float* __restrict__ l2i,
    float* __restrict__ tmp)
{
  __shared__ int4   eo[480];
  __shared__ float4 ew[480];
  const int tid = threadIdx.x;
  const int cellBase = blockIdx.x * 8;

  for (int e = tid; e < 480; e += 320) {
    const int cell = e / 60;
    const int idx = e - cell * 60;
    const int n = idx / 10;
    const int z = idx - n * 10;
    const int cid = cellBase + cell;
    const int gix = cid >> 7;
    const int giy = cid & 127;
    const float X = (float)(-50.8 + (double)gix * (101.6 / 127.0));
    const float Y = (float)(-50.8 + (double)giy * (101.6 / 127.0));
    const float Z = (float)(-4.6 + (double)z * (7.2 / 9.0));
    const float* M = l2i + n * 16;
    const float pw = M[0] * X + M[1] * Y + M[2] * Z + M[3];
    const float ph = M[4] * X + M[5] * Y + M[6] * Z + M[7];
    const float d  = M[8] * X + M[9] * Y + M[10] * Z + M[11];
    const float px = pw / d;
    const float py = ph / d;
    const bool on_img = (px < 704.f) && (px > 0.f) && (py < 256.f) && (py > 0.f) && (d > 0.1f);
    const float gx = px / 704.f * 2.f - 1.f;
    const float gy = py / 256.f * 2.f - 1.f;
    const float ixf = (gx + 1.f) * 0.5f * 87.f;
    const float iyf = (gy + 1.f) * 0.5f * 31.f;
    const float ix0 = floorf(ixf);
    const float iy0 = floorf(iyf);
    const float wx1 = ixf - ix0;
    const float wy1 = iyf - iy0;
    const float ix1 = ix0 + 1.f, iy1 = iy0 + 1.f;
    float w00 = (1.f - wy1) * (1.f - wx1);
    float w01 = (1.f - wy1) * wx1;
    float w10 = wy1 * (1.f - wx1);
    float w11 = wy1 * wx1;
    const bool vx0 = (ix0 >= 0.f) && (ix0 < 88.f);
    const bool vx1 = (ix1 >= 0.f) && (ix1 < 88.f);
    const bool vy0 = (iy0 >= 0.f) && (iy0 < 32.f);
    const bool vy1 = (iy1 >= 0.f) && (iy1 < 32.f);
    if (!(on_img && vy0 && vx0)) w00 = 0.f;
    if (!(on_img && vy0 && vx1)) w01 = 0.f;
    if (!(on_img && vy1 && vx0)) w10 = 0.f;
    if (!(on_img && vy1 && vx1)) w11 = 0.f;
    const int i0 = (int)fminf(fmaxf(ix0, 0.f), 87.f);
    const int i1 = (int)fminf(fmaxf(ix1, 0.f), 87.f);
    const int j0 = (int)fminf(fmaxf(iy0, 0.f), 31.f);
    const int j1 = (int)fminf(fmaxf(iy1, 0.f), 31.f);
    const int base = n * SP;
    eo[e] = make_int4((base + j0 * 88 + i0) * COUTC,
                      (base + j0 * 88 + i1) * COUTC,
                      (base + j1 * 88 + i0) * COUTC,
                      (base + j1 * 88 + i1) * COUTC);
    ew[e] = make_float4(w00, w01, w10, w11);
  }
  __syncthreads();

  const int c2 = (tid % 40) * 2;
  const int cell = tid / 40;
  const int ebase = cell * 60;
  float a0 = 0.f, a1 = 0.f;
  for (int z = 0; z < 10; ++z) {
    float mx0 = -INFINITY, mx1 = -INFINITY;
    #pragma unroll
    for (int n = 0; n < 6; ++n) {
      const int4   o = eo[ebase + n * 10 + z];
      const float4 w = ew[ebase + n * 10 + z];
      const half2v p00 = *(const half2v*)(feat + o.x + c2);
      const half2v p01 = *(const half2v*)(feat + o.y + c2);
      const half2v p10 = *(const half2v*)(feat + o.z + c2);
      const half2v p11 = *(const half2v*)(feat + o.w + c2);
      float v0 = w.x * (float)p00[0];
      float v1 = w.x * (float)p00[1];
      v0 = fmaf(w.y, (float)p01[0], v0);  v1 = fmaf(w.y, (float)p01[1], v1);
      v0 = fmaf(w.z, (float)p10[0], v0);  v1 = fmaf(w.z, (float)p10[1], v1);
      v0 = fmaf(w.w, (float)p11[0], v0);  v1 = fmaf(w.w, (float)p11[1], v1);
      mx0 = fmaxf(mx0, v0);
      mx1 = fmaxf(mx1, v1);
    }
    a0 += mx0;
    a1 += mx1;
  }
  const int cid = cellBase + cell;
  float2 res = make_float2(a0 * 0.1f, a1 * 0.1f);
  *(float2*)(&tmp[(size_t)cid * COUTC + c2]) = res;
}

// ---------------- [16384][80] -> [80][16384] transpose ----------------
__global__ __launch_bounds__(256) void bev_transpose(const float* __restrict__ tmp,
                                                     float* __restrict__ out)
{
  __shared__ float tile[32][33];
  const int mBase = blockIdx.x * 32;
  const int cBase = blockIdx.y * 32;
  const int tx = threadIdx.x & 31;
  const int ty = threadIdx.x >> 5;   // 0..7
  for (int i = ty; i < 32; i += 8) {
    const int cc = cBase + tx;
    tile[i][tx] = (cc < COUTC) ? tmp[(size_t)(mBase + i) * COUTC + cc] : 0.f;
  }
  __syncthreads();
  for (int i = ty; i < 32; i += 8) {
    const int cc = cBase + i;
    if (cc < COUTC) out[(size_t)cc * 16384 + mBase + tx] = tile[tx][i];
  }
}

extern "C" void kernel_launch(void* const* d_in, const int* in_sizes, int n_in,
                              void* d_out, int out_size, void* d_ws, size_t ws_size,
                              hipStream_t stream)
{
  const float* img = (const float*)d_in[0];
  const float* l2i = (const float*)d_in[1];
  const float* w1  = (const float*)d_in[2];
  const float* b1  = (const float*)d_in[3];
  const float* g1  = (const float*)d_in[4];
  const float* be1 = (const float*)d_in[5];
  const float* m1  = (const float*)d_in[6];
  const float* v1  = (const float*)d_in[7];
  const float* w2  = (const float*)d_in[8];
  const float* b2  = (const float*)d_in[9];
  const float* g2  = (const float*)d_in[10];
  const float* be2 = (const float*)d_in[11];
  const float* m2  = (const float*)d_in[12];
  const float* v2  = (const float*)d_in[13];
  const float* w3  = (const float*)d_in[14];
  const float* b3  = (const float*)d_in[15];

  char* ws = (char*)d_ws;
  _Float16* wT1h = (_Float16*)ws;  ws += (size_t)9 * CIN * CIN * 2;
  _Float16* wT2h = (_Float16*)ws;  ws += (size_t)9 * CIN * CIN * 2;
  _Float16* wT3h = (_Float16*)ws;  ws += (size_t)CIN * COUTC * 2;
  _Float16* x0   = (_Float16*)ws;  ws += (size_t)N_IMG * SPH * CIN * 2;
  _Float16* x1h  = (_Float16*)ws;  ws += (size_t)N_IMG * SPH * CIN * 2;
  _Float16* x2h  = (_Float16*)ws;  ws += (size_t)N_IMG * SP * CIN * 2;
  _Float16* feat = (_Float16*)ws;  ws += (size_t)N_IMG * SP * COUTC * 2;
  float*    tmp  = (float*)ws;
  float*    outp = (float*)d_out;

  // zero halos (whole buffers; interiors overwritten downstream)
  hipMemsetAsync(x0,  0, (size_t)N_IMG * SPH * CIN * 2, stream);
  hipMemsetAsync(x1h, 0, (size_t)N_IMG * SPH * CIN * 2, stream);

  prep_w33<<<256, 256, 0, stream>>>(w1, wT1h);
  prep_w33<<<256, 256, 0, stream>>>(w2, wT2h);
  prep_w11<<<80, 256, 0, stream>>>(w3, wT3h);
  nchw_to_nhwc<<<dim3(44, 4, 6), 256, 0, stream>>>(img, x0);

  conv3x3_mfma<<<dim3(22, 4, 6), 256, 0, stream>>>(x0, wT1h, b1, g1, be1, m1, v1,
                                                   x1h, WW, WW + 1, SPH);
  conv3x3_mfma<<<dim3(22, 4, 6), 256, 0, stream>>>(x1h, wT2h, b2, g2, be2, m2, v2,
                                                   x2h, 88, 0, SP);
  conv1x1_mfma<<<132, 256, 0, stream>>>(x2h, wT3h, b3, feat);

  bev_sample<<<2048, 320, 0, stream>>>(feat, l2i, tmp);
  bev_transpose<<<dim3(512, 3), 256, 0, stream>>>(tmp, outp);
}

// Round 4
// 279.610 us; speedup vs baseline: 1.0940x; 1.0940x over previous
//
#include <hip/hip_runtime.h>
#include <math.h>

#define N_IMG 6
#define CIN   256
#define H_IN  32
#define W_IN  88
#define SP    2816      // 32*88
#define HH    34        // H+2 halo
#define WW    90        // W+2 halo
#define SPH   3060      // 34*90
#define COUTC 80
#define EPSBN 1e-5f

typedef _Float16 half8 __attribute__((ext_vector_type(8)));
typedef _Float16 half2v __attribute__((ext_vector_type(2)));
typedef float floatx4 __attribute__((ext_vector_type(4)));

// ---------------- weight prep ----------------
// w (OIHW [256][256][3][3]) -> fp16 [tap][oc][ic]
__global__ __launch_bounds__(256) void prep_w33(const float* __restrict__ w,
                                                _Float16* __restrict__ wT) {
  __shared__ float s[2304];
  const int oc = blockIdx.x;
  const int tid = threadIdx.x;
  const float* wo = w + (size_t)oc * 2304;
  for (int i = tid; i < 2304; i += 256) s[i] = wo[i];
  __syncthreads();
  for (int i = tid; i < 2304; i += 256) {
    const int tap = i >> 8;
    const int ic  = i & 255;
    wT[((size_t)tap * 256 + oc) * 256 + ic] = (_Float16)s[ic * 9 + tap];
  }
}

// w3 [80][256] -> fp16 (plain cast copy, [oc][ic])
__global__ __launch_bounds__(256) void prep_w11(const float* __restrict__ w,
                                                _Float16* __restrict__ wT) {
  int idx = blockIdx.x * 256 + threadIdx.x;
  if (idx >= CIN * COUTC) return;
  wT[idx] = (_Float16)w[idx];
}

// img fp32 NCHW -> fp16 NHWC with zero halo ([im][34][90][256])
__global__ __launch_bounds__(256) void nchw_to_nhwc(const float* __restrict__ img,
                                                    _Float16* __restrict__ x0) {
  __shared__ float t[64][65];
  const int sp0 = blockIdx.x * 64;
  const int ic0 = blockIdx.y * 64;
  const int im  = blockIdx.z;
  const int tx = threadIdx.x & 63;
  const int ty = threadIdx.x >> 6;   // 0..3
  for (int r = ty; r < 64; r += 4)
    t[r][tx] = img[((size_t)(im * CIN + ic0 + r)) * SP + sp0 + tx];
  __syncthreads();
  for (int r = ty; r < 64; r += 4) {
    const int sp = sp0 + r;
    const int h = sp / 88;
    const int w = sp - h * 88;
    x0[((size_t)im * SPH + h * WW + w + WW + 1) * CIN + ic0 + tx] = (_Float16)t[tx][r];
  }
}

// ---------------- 3x3 conv + BN + ReLU, halo-stationary MFMA ----------------
// block: 128 threads (2 waves). M-tile = 16 rows x 8 cols = 128 spatial, N=64 oc.
// wave tile 64x64. A: halo (18x10 pos, padded to 192) staged per ic-quarter via
// global_load_lds with XOR granule swizzle. B: global->reg->LDS double-buffered.
__global__ __launch_bounds__(128) void conv3x3_mfma(
    const _Float16* __restrict__ x, const _Float16* __restrict__ wT,
    const float* __restrict__ bias, const float* __restrict__ gamma,
    const float* __restrict__ beta, const float* __restrict__ bnm,
    const float* __restrict__ bnv, _Float16* __restrict__ out,
    int OW, int OB, int imStride)
{
  __shared__ _Float16 Ah[192 * 64];      // [pos][granule-phys 8][8 halfs]
  __shared__ _Float16 Bsm[2 * 64 * 72];  // [buf][oc 64][ic 64 + pad 8]

  const int tid  = threadIdx.x;
  const int wv   = tid >> 6;
  const int lane = tid & 63;
  const int th   = blockIdx.x & 1;       // 0..1  (H0)
  const int tw   = blockIdx.x >> 1;      // 0..10 (W0)
  const int H0   = th * 16;
  const int W0   = tw * 8;
  const int n0   = blockIdx.y * 64;
  const int im   = blockIdx.z;
  const _Float16* xim = x + (size_t)im * SPH * CIN;

  // --- A-DMA per-lane source offsets (12 issues per wave, 8 pos rows each) ---
  const int lr = lane >> 3;              // pos-row within group of 8
  const int gl = (lane & 7) ^ lr;        // logical granule (pos&7 == lr)
  int srcOff[12];
  #pragma unroll
  for (int i = 0; i < 12; ++i) {
    int pos = (wv * 12 + i) * 8 + lr;
    pos = pos < 179 ? pos : 179;         // rows 180..191 = padding (never read)
    const int hh = pos / 10;
    const int ww = pos - hh * 10;
    srcOff[i] = ((H0 + hh) * WW + (W0 + ww)) * CIN + gl * 8;
  }

  const int fr  = lane & 15;
  const int q   = lane >> 4;             // 0..3
  const int q8  = q * 8;
  const int q4  = q * 4;
  const int fr8 = fr >> 3;
  const int fw  = fr & 7;
  const int mw  = wv * 64;

  // B staging: 512 granules (64 oc x 8 ic-granules), 4 per thread
  int bOc[4], bIc8[4];
  #pragma unroll
  for (int r = 0; r < 4; ++r) {
    const int g = tid + (r << 7);
    bOc[r]  = g >> 3;
    bIc8[r] = (g & 7) << 3;
  }

  floatx4 acc[4][4];
  #pragma unroll
  for (int i = 0; i < 4; ++i)
    #pragma unroll
    for (int j = 0; j < 4; ++j) {
      acc[i][j][0] = 0.f; acc[i][j][1] = 0.f; acc[i][j][2] = 0.f; acc[i][j][3] = 0.f;
    }

  half8 breg[4];
  // prefetch B(tap=0, qc=0)
  #pragma unroll
  for (int r = 0; r < 4; ++r)
    breg[r] = *(const half8*)(wT + ((size_t)(0 * 256 + n0 + bOc[r])) * 256 + 0 * 64 + bIc8[r]);
  // stage A(qc=0)
  #pragma unroll
  for (int i = 0; i < 12; ++i)
    __builtin_amdgcn_global_load_lds(
        (const __attribute__((address_space(1))) void*)(xim + srcOff[i]),
        (__attribute__((address_space(3))) void*)(&Ah[(wv * 12 + i) * 512]),
        16, 0, 0);
  __syncthreads();

  for (int qc = 0; qc < 4; ++qc) {
    for (int tap = 0; tap < 9; ++tap) {
      _Float16* Bb = &Bsm[(tap & 1) * 4608];
      // write staged B regs to LDS
      #pragma unroll
      for (int r = 0; r < 4; ++r)
        *(half8*)(&Bb[bOc[r] * 72 + bIc8[r]]) = breg[r];
      __syncthreads();
      // prefetch next B piece into regs (consumed before next barrier)
      if (tap < 8) {
        #pragma unroll
        for (int r = 0; r < 4; ++r)
          breg[r] = *(const half8*)(wT + ((size_t)((tap + 1) * 256 + n0 + bOc[r])) * 256 + qc * 64 + bIc8[r]);
      } else if (qc < 3) {
        #pragma unroll
        for (int r = 0; r < 4; ++r)
          breg[r] = *(const half8*)(wT + ((size_t)(n0 + bOc[r])) * 256 + (qc + 1) * 64 + bIc8[r]);
      }
      // compute this tap
      const int dy = tap / 3 - 1;
      const int dx = tap - (tap / 3) * 3 - 1;
      const int hb = wv * 8 + dy + 1 + fr8;   // halo row base for this lane
      const int wb = fw + dx + 1;
      int posi[4];
      #pragma unroll
      for (int i = 0; i < 4; ++i) posi[i] = (hb + i * 2) * 10 + wb;
      #pragma unroll
      for (int ks = 0; ks < 2; ++ks) {
        half8 af[4], bf[4];
        #pragma unroll
        for (int i = 0; i < 4; ++i) {
          const int p = posi[i];
          af[i] = *(const half8*)(&Ah[p * 64 + (((ks * 4 + q) ^ (p & 7)) * 8)]);
        }
        #pragma unroll
        for (int j = 0; j < 4; ++j)
          bf[j] = *(const half8*)(&Bb[(j * 16 + fr) * 72 + ks * 32 + q8]);
        #pragma unroll
        for (int i = 0; i < 4; ++i)
          #pragma unroll
          for (int j = 0; j < 4; ++j)
            acc[i][j] = __builtin_amdgcn_mfma_f32_16x16x32_f16(af[i], bf[j], acc[i][j], 0, 0, 0);
      }
      __syncthreads();   // reads of Bb (and, at tap==8, of Ah) complete
    }
    if (qc < 3) {
      // stage A(qc+1) into Ah (all reads finished at the barrier above)
      #pragma unroll
      for (int i = 0; i < 12; ++i)
        __builtin_amdgcn_global_load_lds(
            (const __attribute__((address_space(1))) void*)(xim + srcOff[i] + (qc + 1) * 64),
            (__attribute__((address_space(3))) void*)(&Ah[(wv * 12 + i) * 512]),
            16, 0, 0);
      __syncthreads();
    }
  }

  // epilogue: BN + ReLU, store fp16 NHWC (halo or flat per OW/OB/imStride)
  #pragma unroll
  for (int j = 0; j < 4; ++j) {
    const int oc = n0 + j * 16 + fr;
    const float sc = gamma[oc] * rsqrtf(bnv[oc] + EPSBN);
    const float sh = (bias[oc] - bnm[oc]) * sc + beta[oc];
    #pragma unroll
    for (int i = 0; i < 4; ++i) {
      #pragma unroll
      for (int r = 0; r < 4; ++r) {
        const int m = mw + i * 16 + q4 + r;        // tile-local 0..127
        const int h = H0 + (m >> 3);
        const int w = W0 + (m & 7);
        const float v = fmaxf(fmaf(acc[i][j][r], sc, sh), 0.f);
        out[((size_t)im * imStride + h * OW + w + OB) * CIN + oc] = (_Float16)v;
      }
    }
  }
}

// ---------------- 1x1 conv (256->80) + bias, fp16 MFMA, NHWC fp16 out ----------------
// block: 128 threads (2 waves), tile 64(sp) x 80(oc). B staged once in LDS;
// A-fragments read directly from global (NHWC, contiguous in ic). No inner barriers.
__global__ __launch_bounds__(128) void conv1x1_mfma(
    const _Float16* __restrict__ x, const _Float16* __restrict__ wT,
    const float* __restrict__ bias, _Float16* __restrict__ feat)
{
  __shared__ _Float16 Bs[80 * 264];   // [oc][ic 256 + pad 8]

  const int tid = threadIdx.x;
  const int m0  = blockIdx.x * 64;
  const int wv   = tid >> 6;
  const int lane = tid & 63;
  const int fr  = lane & 15;
  const int q8  = (lane >> 4) * 8;
  const int q4  = (lane >> 4) * 4;

  // stage all of B: 80 oc x 32 granules = 2560 granules, 20 per thread
  for (int g = tid; g < 2560; g += 128) {
    const int oc = g >> 5;
    const int kg8 = (g & 31) << 3;
    *(half8*)(&Bs[oc * 264 + kg8]) = *(const half8*)(wT + oc * 256 + kg8);
  }
  __syncthreads();

  floatx4 acc[2][5];
  #pragma unroll
  for (int i = 0; i < 2; ++i)
    #pragma unroll
    for (int j = 0; j < 5; ++j) {
      acc[i][j][0] = 0.f; acc[i][j][1] = 0.f; acc[i][j][2] = 0.f; acc[i][j][3] = 0.f;
    }

  const _Float16* xa = x + (size_t)(m0 + wv * 32 + fr) * 256 + q8;
  #pragma unroll
  for (int ks = 0; ks < 8; ++ks) {
    half8 af[2], bf[5];
    #pragma unroll
    for (int i = 0; i < 2; ++i)
      af[i] = *(const half8*)(xa + (size_t)i * 16 * 256 + ks * 32);
    #pragma unroll
    for (int j = 0; j < 5; ++j)
      bf[j] = *(const half8*)(&Bs[(j * 16 + fr) * 264 + ks * 32 + q8]);
    #pragma unroll
    for (int i = 0; i < 2; ++i)
      #pragma unroll
      for (int j = 0; j < 5; ++j)
        acc[i][j] = __builtin_amdgcn_mfma_f32_16x16x32_f16(af[i], bf[j], acc[i][j], 0, 0, 0);
  }

  #pragma unroll
  for (int j = 0; j < 5; ++j) {
    const int oc = j * 16 + fr;
    const float bb = bias[oc];
    #pragma unroll
    for (int i = 0; i < 2; ++i) {
      const int mbase = m0 + wv * 32 + i * 16 + q4;
      #pragma unroll
      for (int r = 0; r < 4; ++r)
        feat[(size_t)(mbase + r) * COUTC + oc] = (_Float16)(acc[i][j][r] + bb);
    }
  }
}

// ---------------- projection + bilinear + max over cams + mean over z ----------------
// block: 320 threads = 8 cells x 40 channel-pairs. feat fp16 NHWC.
__global__ __launch_bounds__(320) void bev_sample(
    const _Float16* __restrict__ feat, const float* __restrict__ l2i,
    float* __restrict__ tmp)
{
  __shared__ int4   eo[480];
  __shared__ float4 ew[480];
  const int tid = threadIdx.x;
  const int cellBase = blockIdx.x * 8;

  for (int e = tid; e < 480; e += 320) {
    const int cell = e / 60;
    const int idx = e - cell * 60;
    const int n = idx / 10;
    const int z = idx - n * 10;
    const int cid = cellBase + cell;
    const int gix = cid >> 7;
    const int giy = cid & 127;
    const float X = (float)(-50.8 + (double)gix * (101.6 / 127.0));
    const float Y = (float)(-50.8 + (double)giy * (101.6 / 127.0));
    const float Z = (float)(-4.6 + (double)z * (7.2 / 9.0));
    const float* M = l2i + n * 16;
    const float pw = M[0] * X + M[1] * Y + M[2] * Z + M[3];
    const float ph = M[4] * X + M[5] * Y + M[6] * Z + M[7];
    const float d  = M[8] * X + M[9] * Y + M[10] * Z + M[11];
    const float px = pw / d;
    const float py = ph / d;
    const bool on_img = (px < 704.f) && (px > 0.f) && (py < 256.f) && (py > 0.f) && (d > 0.1f);
    const float gx = px / 704.f * 2.f - 1.f;
    const float gy = py / 256.f * 2.f - 1.f;
    const float ixf = (gx + 1.f) * 0.5f * 87.f;
    const float iyf = (gy + 1.f) * 0.5f * 31.f;
    const float ix0 = floorf(ixf);
    const float iy0 = floorf(iyf);
    const float wx1 = ixf - ix0;
    const float wy1 = iyf - iy0;
    const float ix1 = ix0 + 1.f, iy1 = iy0 + 1.f;
    float w00 = (1.f - wy1) * (1.f - wx1);
    float w01 = (1.f - wy1) * wx1;
    float w10 = wy1 * (1.f - wx1);
    float w11 = wy1 * wx1;
    const bool vx0 = (ix0 >= 0.f) && (ix0 < 88.f);
    const bool vx1 = (ix1 >= 0.f) && (ix1 < 88.f);
    const bool vy0 = (iy0 >= 0.f) && (iy0 < 32.f);
    const bool vy1 = (iy1 >= 0.f) && (iy1 < 32.f);
    if (!(on_img && vy0 && vx0)) w00 = 0.f;
    if (!(on_img && vy0 && vx1)) w01 = 0.f;
    if (!(on_img && vy1 && vx0)) w10 = 0.f;
    if (!(on_img && vy1 && vx1)) w11 = 0.f;
    const int i0 = (int)fminf(fmaxf(ix0, 0.f), 87.f);
    const int i1 = (int)fminf(fmaxf(ix1, 0.f), 87.f);
    const int j0 = (int)fminf(fmaxf(iy0, 0.f), 31.f);
    const int j1 = (int)fminf(fmaxf(iy1, 0.f), 31.f);
    const int base = n * SP;
    eo[e] = make_int4((base + j0 * 88 + i0) * COUTC,
                      (base + j0 * 88 + i1) * COUTC,
                      (base + j1 * 88 + i0) * COUTC,
                      (base + j1 * 88 + i1) * COUTC);
    ew[e] = make_float4(w00, w01, w10, w11);
  }
  __syncthreads();

  const int c2 = (tid % 40) * 2;
  const int cell = tid / 40;
  const int ebase = cell * 60;
  float a0 = 0.f, a1 = 0.f;
  for (int z = 0; z < 10; ++z) {
    float mx0 = -INFINITY, mx1 = -INFINITY;
    #pragma unroll
    for (int n = 0; n < 6; ++n) {
      const float4 w = ew[ebase + n * 10 + z];
      if (w.x + w.y + w.z + w.w > 0.f) {
        const int4 o = eo[ebase + n * 10 + z];
        const half2v p00 = *(const half2v*)(feat + o.x + c2);
        const half2v p01 = *(const half2v*)(feat + o.y + c2);
        const half2v p10 = *(const half2v*)(feat + o.z + c2);
        const half2v p11 = *(const half2v*)(feat + o.w + c2);
        float v0 = w.x * (float)p00[0];
        float v1 = w.x * (float)p00[1];
        v0 = fmaf(w.y, (float)p01[0], v0);  v1 = fmaf(w.y, (float)p01[1], v1);
        v0 = fmaf(w.z, (float)p10[0], v0);  v1 = fmaf(w.z, (float)p10[1], v1);
        v0 = fmaf(w.w, (float)p11[0], v0);  v1 = fmaf(w.w, (float)p11[1], v1);
        mx0 = fmaxf(mx0, v0);
        mx1 = fmaxf(mx1, v1);
      } else {
        mx0 = fmaxf(mx0, 0.f);
        mx1 = fmaxf(mx1, 0.f);
      }
    }
    a0 += mx0;
    a1 += mx1;
  }
  const int cid = cellBase + cell;
  float2 res = make_float2(a0 * 0.1f, a1 * 0.1f);
  *(float2*)(&tmp[(size_t)cid * COUTC + c2]) = res;
}

// ---------------- [16384][80] -> [80][16384] transpose ----------------
__global__ __launch_bounds__(256) void bev_transpose(const float* __restrict__ tmp,
                                                     float* __restrict__ out)
{
  __shared__ float tile[32][33];
  const int mBase = blockIdx.x * 32;
  const int cBase = blockIdx.y * 32;
  const int tx = threadIdx.x & 31;
  const int ty = threadIdx.x >> 5;   // 0..7
  for (int i = ty; i < 32; i += 8) {
    const int cc = cBase + tx;
    tile[i][tx] = (cc < COUTC) ? tmp[(size_t)(mBase + i) * COUTC + cc] : 0.f;
  }
  __syncthreads();
  for (int i = ty; i < 32; i += 8) {
    const int cc = cBase + i;
    if (cc < COUTC) out[(size_t)cc * 16384 + mBase + tx] = tile[tx][i];
  }
}

extern "C" void kernel_launch(void* const* d_in, const int* in_sizes, int n_in,
                              void* d_out, int out_size, void* d_ws, size_t ws_size,
                              hipStream_t stream)
{
  const float* img = (const float*)d_in[0];
  const float* l2i = (const float*)d_in[1];
  const float* w1  = (const float*)d_in[2];
  const float* b1  = (const float*)d_in[3];
  const float* g1  = (const float*)d_in[4];
  const float* be1 = (const float*)d_in[5];
  const float* m1  = (const float*)d_in[6];
  const float* v1  = (const float*)d_in[7];
  const float* w2  = (const float*)d_in[8];
  const float* b2  = (const float*)d_in[9];
  const float* g2  = (const float*)d_in[10];
  const float* be2 = (const float*)d_in[11];
  const float* m2  = (const float*)d_in[12];
  const float* v2  = (const float*)d_in[13];
  const float* w3  = (const float*)d_in[14];
  const float* b3  = (const float*)d_in[15];

  char* ws = (char*)d_ws;
  _Float16* wT1h = (_Float16*)ws;  ws += (size_t)9 * CIN * CIN * 2;
  _Float16* wT2h = (_Float16*)ws;  ws += (size_t)9 * CIN * CIN * 2;
  _Float16* wT3h = (_Float16*)ws;  ws += (size_t)CIN * COUTC * 2;
  _Float16* x0   = (_Float16*)ws;  ws += (size_t)N_IMG * SPH * CIN * 2;
  _Float16* x1h  = (_Float16*)ws;  ws += (size_t)N_IMG * SPH * CIN * 2;
  _Float16* x2h  = (_Float16*)ws;  ws += (size_t)N_IMG * SP * CIN * 2;
  _Float16* feat = (_Float16*)ws;  ws += (size_t)N_IMG * SP * COUTC * 2;
  float*    tmp  = (float*)ws;
  float*    outp = (float*)d_out;

  // zero halos (whole buffers; interiors overwritten downstream)
  hipMemsetAsync(x0,  0, (size_t)N_IMG * SPH * CIN * 2, stream);
  hipMemsetAsync(x1h, 0, (size_t)N_IMG * SPH * CIN * 2, stream);

  prep_w33<<<256, 256, 0, stream>>>(w1, wT1h);
  prep_w33<<<256, 256, 0, stream>>>(w2, wT2h);
  prep_w11<<<80, 256, 0, stream>>>(w3, wT3h);
  nchw_to_nhwc<<<dim3(44, 4, 6), 256, 0, stream>>>(img, x0);

  conv3x3_mfma<<<dim3(22, 4, 6), 128, 0, stream>>>(x0, wT1h, b1, g1, be1, m1, v1,
                                                   x1h, WW, WW + 1, SPH);
  conv3x3_mfma<<<dim3(22, 4, 6), 128, 0, stream>>>(x1h, wT2h, b2, g2, be2, m2, v2,
                                                   x2h, 88, 0, SP);
  conv1x1_mfma<<<264, 128, 0, stream>>>(x2h, wT3h, b3, feat);

  bev_sample<<<2048, 320, 0, stream>>>(feat, l2i, tmp);
  bev_transpose<<<dim3(512, 3), 256, 0, stream>>>(tmp, outp);
}

// Round 6
// 223.107 us; speedup vs baseline: 1.3710x; 1.2533x over previous
//
#include <hip/hip_runtime.h>
#include <math.h>

#define N_IMG 6
#define CIN   256
#define H_IN  32
#define W_IN  88
#define SP    2816      // 32*88
#define HH    34        // H+2 halo
#define WW    90        // W+2 halo
#define SPH   3060      // 34*90
#define COUTC 80
#define EPSBN 1e-5f

typedef _Float16 half8 __attribute__((ext_vector_type(8)));
typedef _Float16 half2v __attribute__((ext_vector_type(2)));
typedef float floatx4 __attribute__((ext_vector_type(4)));

#define AS1 __attribute__((address_space(1)))
#define AS3 __attribute__((address_space(3)))

// ---------------- zero halo borders of x0 and x1h ----------------
__global__ __launch_bounds__(256) void zero_halo(_Float16* __restrict__ a,
                                                 _Float16* __restrict__ b) {
  const int im = blockIdx.x;
  const int tid = threadIdx.x;
  for (int s = tid; s < 244 * 32; s += 256) {
    const int pos = s >> 5;
    const int gr  = s & 31;
    int h, w;
    if (pos < 90)       { h = 0;  w = pos; }
    else if (pos < 180) { h = 33; w = pos - 90; }
    else { const int r = pos - 180; h = 1 + (r >> 1); w = (r & 1) * 89; }
    const size_t off = ((size_t)im * SPH + h * WW + w) * CIN + gr * 8;
    half8 z = {};
    *(half8*)(a + off) = z;
    *(half8*)(b + off) = z;
  }
}

// ---------------- weight prep ----------------
// w (OIHW [256][256][3][3]) -> fp16 [tap][oc][ic]; blockIdx.y picks layer
__global__ __launch_bounds__(256) void prep_w33(const float* __restrict__ wa,
                                                const float* __restrict__ wb,
                                                _Float16* __restrict__ wTa,
                                                _Float16* __restrict__ wTb) {
  __shared__ float s[2304];
  const int oc = blockIdx.x;
  const int tid = threadIdx.x;
  const float* w = blockIdx.y ? wb : wa;
  _Float16* wT = blockIdx.y ? wTb : wTa;
  const float* wo = w + (size_t)oc * 2304;
  for (int i = tid; i < 2304; i += 256) s[i] = wo[i];
  __syncthreads();
  for (int i = tid; i < 2304; i += 256) {
    const int tap = i >> 8;
    const int ic  = i & 255;
    wT[((size_t)tap * 256 + oc) * 256 + ic] = (_Float16)s[ic * 9 + tap];
  }
}

// w3 [80][256] -> fp16 (plain cast copy, [oc][ic])
__global__ __launch_bounds__(256) void prep_w11(const float* __restrict__ w,
                                                _Float16* __restrict__ wT) {
  int idx = blockIdx.x * 256 + threadIdx.x;
  if (idx >= CIN * COUTC) return;
  wT[idx] = (_Float16)w[idx];
}

// img fp32 NCHW -> fp16 NHWC with zero halo ([im][34][90][256])
__global__ __launch_bounds__(256) void nchw_to_nhwc(const float* __restrict__ img,
                                                    _Float16* __restrict__ x0) {
  __shared__ float t[64][65];
  const int sp0 = blockIdx.x * 64;
  const int ic0 = blockIdx.y * 64;
  const int im  = blockIdx.z;
  const int tx = threadIdx.x & 63;
  const int ty = threadIdx.x >> 6;   // 0..3
  for (int r = ty; r < 64; r += 4)
    t[r][tx] = img[((size_t)(im * CIN + ic0 + r)) * SP + sp0 + tx];
  __syncthreads();
  for (int r = ty; r < 64; r += 4) {
    const int sp = sp0 + r;
    const int h = sp / 88;
    const int w = sp - h * 88;
    x0[((size_t)im * SPH + h * WW + w + WW + 1) * CIN + ic0 + tx] = (_Float16)t[tx][r];
  }
}

// ---------------- 3x3 conv + BN + ReLU, m97-style fp16 MFMA implicit GEMM ----
// block: 256 threads (4 waves, 2Mx2N, wave 64x64). tile 128(sp) x 128(oc),
// BK=64 over (tap, ic-quarter): 36 chunks. A and B both staged via
// global_load_lds (16B/lane, 4 issues EACH = 1024 granules each) into
// pitch-64 XOR-granule-swizzled LDS.
__global__ __launch_bounds__(256) void conv3x3_mfma(
    const _Float16* __restrict__ x, const _Float16* __restrict__ wT,
    const float* __restrict__ bias, const float* __restrict__ gamma,
    const float* __restrict__ beta, const float* __restrict__ bnm,
    const float* __restrict__ bnv, _Float16* __restrict__ out,
    int OW, int OB, int imStride)
{
  __shared__ _Float16 As[128 * 64];   // [row][phys-granule 8][8]  (16 KB)
  __shared__ _Float16 Bs[128 * 64];   // [oc ][phys-granule 8][8]  (16 KB)

  const int tid  = threadIdx.x;
  const int wv   = tid >> 6;
  const int lane = tid & 63;
  const int m0   = blockIdx.x * 128;
  const int n0   = blockIdx.y * 128;
  const int im   = blockIdx.z;
  const _Float16* xim = x + (size_t)im * SPH * CIN;

  // per-thread staging source offsets (granule XOR swizzle on the source)
  int srcA[4], srcB[4];
  #pragma unroll
  for (int i = 0; i < 4; ++i) {
    const int g = i * 256 + wv * 64 + lane;
    const int row = g >> 3;
    const int lg  = (g & 7) ^ (row & 7);
    const int m = m0 + row;
    const int h = m / 88;
    const int w = m - h * 88;
    srcA[i] = ((h + 1) * WW + (w + 1)) * CIN + lg * 8;
    srcB[i] = (n0 + row) * 256 + lg * 8;
  }

  const int fr = lane & 15;
  const int q  = lane >> 4;        // 0..3
  const int q4 = q * 4;
  const int mw = (wv & 1) * 64;
  const int nw = (wv >> 1) * 64;

  floatx4 acc[4][4];
  #pragma unroll
  for (int i = 0; i < 4; ++i)
    #pragma unroll
    for (int j = 0; j < 4; ++j) {
      acc[i][j][0] = 0.f; acc[i][j][1] = 0.f; acc[i][j][2] = 0.f; acc[i][j][3] = 0.f;
    }

  for (int tap = 0; tap < 9; ++tap) {
    const int dy = tap / 3 - 1;
    const int dx = tap - (tap / 3) * 3 - 1;
    const int aoff = (dy * WW + dx) * CIN;
    const size_t boff = (size_t)tap * 65536;

    for (int icc = 0; icc < 256; icc += 64) {
      #pragma unroll
      for (int i = 0; i < 4; ++i)
        __builtin_amdgcn_global_load_lds(
            (const AS1 void*)(xim + srcA[i] + aoff + icc),
            (AS3 void*)(&As[(i * 256 + wv * 64) * 8]), 16, 0, 0);
      #pragma unroll
      for (int i = 0; i < 4; ++i)
        __builtin_amdgcn_global_load_lds(
            (const AS1 void*)(wT + boff + srcB[i] + icc),
            (AS3 void*)(&Bs[(i * 256 + wv * 64) * 8]), 16, 0, 0);
      __syncthreads();

      #pragma unroll
      for (int ks = 0; ks < 2; ++ks) {
        half8 af[4], bf[4];
        #pragma unroll
        for (int i = 0; i < 4; ++i) {
          const int row = mw + i * 16 + fr;
          af[i] = *(const half8*)(&As[row * 64 + (((ks * 4 + q) ^ (row & 7)) * 8)]);
        }
        #pragma unroll
        for (int j = 0; j < 4; ++j) {
          const int row = nw + j * 16 + fr;
          bf[j] = *(const half8*)(&Bs[row * 64 + (((ks * 4 + q) ^ (row & 7)) * 8)]);
        }
        #pragma unroll
        for (int i = 0; i < 4; ++i)
          #pragma unroll
          for (int j = 0; j < 4; ++j)
            acc[i][j] = __builtin_amdgcn_mfma_f32_16x16x32_f16(af[i], bf[j], acc[i][j], 0, 0, 0);
      }
      __syncthreads();
    }
  }

  // epilogue: BN + ReLU, store fp16 NHWC (halo or flat per OW/OB/imStride)
  #pragma unroll
  for (int j = 0; j < 4; ++j) {
    const int oc = n0 + nw + j * 16 + fr;
    const float sc = gamma[oc] * rsqrtf(bnv[oc] + EPSBN);
    const float sh = (bias[oc] - bnm[oc]) * sc + beta[oc];
    #pragma unroll
    for (int i = 0; i < 4; ++i) {
      #pragma unroll
      for (int r = 0; r < 4; ++r) {
        const int m = m0 + mw + i * 16 + q4 + r;
        const int h = m / 88;
        const int w = m - h * 88;
        const float v = fmaxf(fmaf(acc[i][j][r], sc, sh), 0.f);
        out[((size_t)im * imStride + h * OW + w + OB) * CIN + oc] = (_Float16)v;
      }
    }
  }
}

// ---------------- 1x1 conv (256->80) + bias, fp16 MFMA, NHWC fp16 out --------
// block: 128 threads (2 waves), tile 64(sp) x 80(oc). B staged once in LDS;
// A-fragments read directly from global (NHWC, contiguous in ic).
__global__ __launch_bounds__(128) void conv1x1_mfma(
    const _Float16* __restrict__ x, const _Float16* __restrict__ wT,
    const float* __restrict__ bias, _Float16* __restrict__ feat)
{
  __shared__ _Float16 Bs[80 * 264];   // [oc][ic 256 + pad 8]

  const int tid = threadIdx.x;
  const int m0  = blockIdx.x * 64;
  const int wv   = tid >> 6;
  const int lane = tid & 63;
  const int fr  = lane & 15;
  const int q8  = (lane >> 4) * 8;
  const int q4  = (lane >> 4) * 4;

  for (int g = tid; g < 2560; g += 128) {
    const int oc = g >> 5;
    const int kg8 = (g & 31) << 3;
    *(half8*)(&Bs[oc * 264 + kg8]) = *(const half8*)(wT + oc * 256 + kg8);
  }
  __syncthreads();

  floatx4 acc[2][5];
  #pragma unroll
  for (int i = 0; i < 2; ++i)
    #pragma unroll
    for (int j = 0; j < 5; ++j) {
      acc[i][j][0] = 0.f; acc[i][j][1] = 0.f; acc[i][j][2] = 0.f; acc[i][j][3] = 0.f;
    }

  const _Float16* xa = x + (size_t)(m0 + wv * 32 + fr) * 256 + q8;
  #pragma unroll
  for (int ks = 0; ks < 8; ++ks) {
    half8 af[2], bf[5];
    #pragma unroll
    for (int i = 0; i < 2; ++i)
      af[i] = *(const half8*)(xa + (size_t)i * 16 * 256 + ks * 32);
    #pragma unroll
    for (int j = 0; j < 5; ++j)
      bf[j] = *(const half8*)(&Bs[(j * 16 + fr) * 264 + ks * 32 + q8]);
    #pragma unroll
    for (int i = 0; i < 2; ++i)
      #pragma unroll
      for (int j = 0; j < 5; ++j)
        acc[i][j] = __builtin_amdgcn_mfma_f32_16x16x32_f16(af[i], bf[j], acc[i][j], 0, 0, 0);
  }

  #pragma unroll
  for (int j = 0; j < 5; ++j) {
    const int oc = j * 16 + fr;
    const float bb = bias[oc];
    #pragma unroll
    for (int i = 0; i < 2; ++i) {
      const int mbase = m0 + wv * 32 + i * 16 + q4;
      #pragma unroll
      for (int r = 0; r < 4; ++r)
        feat[(size_t)(mbase + r) * COUTC + oc] = (_Float16)(acc[i][j][r] + bb);
    }
  }
}

// ---------------- projection + bilinear + max over cams + mean over z --------
// block: 320 threads = 8 cells x 40 channel-pairs. feat fp16 NHWC.
__global__ __launch_bounds__(320) void bev_sample(
    const _Float16* __restrict__ feat, const float* __restrict__ l2i,
    float* __restrict__ tmp)
{
  __shared__ int4   eo[480];
  __shared__ float4 ew[480];
  const int tid = threadIdx.x;
  const int cellBase = blockIdx.x * 8;

  for (int e = tid; e < 480; e += 320) {
    const int cell = e / 60;
    const int idx = e - cell * 60;
    const int n = idx / 10;
    const int z = idx - n * 10;
    const int cid = cellBase + cell;
    const int gix = cid >> 7;
    const int giy = cid & 127;
    const float X = (float)(-50.8 + (double)gix * (101.6 / 127.0));
    const float Y = (float)(-50.8 + (double)giy * (101.6 / 127.0));
    const float Z = (float)(-4.6 + (double)z * (7.2 / 9.0));
    const float* M = l2i + n * 16;
    const float pw = M[0] * X + M[1] * Y + M[2] * Z + M[3];
    const float ph = M[4] * X + M[5] * Y + M[6] * Z + M[7];
    const float d  = M[8] * X + M[9] * Y + M[10] * Z + M[11];
    const float px = pw / d;
    const float py = ph / d;
    const bool on_img = (px < 704.f) && (px > 0.f) && (py < 256.f) && (py > 0.f) && (d > 0.1f);
    const float gx = px / 704.f * 2.f - 1.f;
    const float gy = py / 256.f * 2.f - 1.f;
    const float ixf = (gx + 1.f) * 0.5f * 87.f;
    const float iyf = (gy + 1.f) * 0.5f * 31.f;
    const float ix0 = floorf(ixf);
    const float iy0 = floorf(iyf);
    const float wx1 = ixf - ix0;
    const float wy1 = iyf - iy0;
    const float ix1 = ix0 + 1.f, iy1 = iy0 + 1.f;
    float w00 = (1.f - wy1) * (1.f - wx1);
    float w01 = (1.f - wy1) * wx1;
    float w10 = wy1 * (1.f - wx1);
    float w11 = wy1 * wx1;
    const bool vx0 = (ix0 >= 0.f) && (ix0 < 88.f);
    const bool vx1 = (ix1 >= 0.f) && (ix1 < 88.f);
    const bool vy0 = (iy0 >= 0.f) && (iy0 < 32.f);
    const bool vy1 = (iy1 >= 0.f) && (iy1 < 32.f);
    if (!(on_img && vy0 && vx0)) w00 = 0.f;
    if (!(on_img && vy0 && vx1)) w01 = 0.f;
    if (!(on_img && vy1 && vx0)) w10 = 0.f;
    if (!(on_img && vy1 && vx1)) w11 = 0.f;
    const int i0 = (int)fminf(fmaxf(ix0, 0.f), 87.f);
    const int i1 = (int)fminf(fmaxf(ix1, 0.f), 87.f);
    const int j0 = (int)fminf(fmaxf(iy0, 0.f), 31.f);
    const int j1 = (int)fminf(fmaxf(iy1, 0.f), 31.f);
    const int base = n * SP;
    eo[e] = make_int4((base + j0 * 88 + i0) * COUTC,
                      (base + j0 * 88 + i1) * COUTC,
                      (base + j1 * 88 + i0) * COUTC,
                      (base + j1 * 88 + i1) * COUTC);
    ew[e] = make_float4(w00, w01, w10, w11);
  }
  __syncthreads();

  const int c2 = (tid % 40) * 2;
  const int cell = tid / 40;
  const int ebase = cell * 60;
  float a0 = 0.f, a1 = 0.f;
  for (int z = 0; z < 10; ++z) {
    float mx0 = -INFINITY, mx1 = -INFINITY;
    #pragma unroll
    for (int n = 0; n < 6; ++n) {
      const float4 w = ew[ebase + n * 10 + z];
      if (w.x + w.y + w.z + w.w > 0.f) {
        const int4 o = eo[ebase + n * 10 + z];
        const half2v p00 = *(const half2v*)(feat + o.x + c2);
        const half2v p01 = *(const half2v*)(feat + o.y + c2);
        const half2v p10 = *(const half2v*)(feat + o.z + c2);
        const half2v p11 = *(const half2v*)(feat + o.w + c2);
        float v0 = w.x * (float)p00[0];
        float v1 = w.x * (float)p00[1];
        v0 = fmaf(w.y, (float)p01[0], v0);  v1 = fmaf(w.y, (float)p01[1], v1);
        v0 = fmaf(w.z, (float)p10[0], v0);  v1 = fmaf(w.z, (float)p10[1], v1);
        v0 = fmaf(w.w, (float)p11[0], v0);  v1 = fmaf(w.w, (float)p11[1], v1);
        mx0 = fmaxf(mx0, v0);
        mx1 = fmaxf(mx1, v1);
      } else {
        mx0 = fmaxf(mx0, 0.f);
        mx1 = fmaxf(mx1, 0.f);
      }
    }
    a0 += mx0;
    a1 += mx1;
  }
  const int cid = cellBase + cell;
  float2 res = make_float2(a0 * 0.1f, a1 * 0.1f);
  *(float2*)(&tmp[(size_t)cid * COUTC + c2]) = res;
}

// ---------------- [16384][80] -> [80][16384] transpose ----------------
__global__ __launch_bounds__(256) void bev_transpose(const float* __restrict__ tmp,
                                                     float* __restrict__ out)
{
  __shared__ float tile[32][33];
  const int mBase = blockIdx.x * 32;
  const int cBase = blockIdx.y * 32;
  const int tx = threadIdx.x & 31;
  const int ty = threadIdx.x >> 5;   // 0..7
  for (int i = ty; i < 32; i += 8) {
    const int cc = cBase + tx;
    tile[i][tx] = (cc < COUTC) ? tmp[(size_t)(mBase + i) * COUTC + cc] : 0.f;
  }
  __syncthreads();
  for (int i = ty; i < 32; i += 8) {
    const int cc = cBase + i;
    if (cc < COUTC) out[(size_t)cc * 16384 + mBase + tx] = tile[tx][i];
  }
}

extern "C" void kernel_launch(void* const* d_in, const int* in_sizes, int n_in,
                              void* d_out, int out_size, void* d_ws, size_t ws_size,
                              hipStream_t stream)
{
  const float* img = (const float*)d_in[0];
  const float* l2i = (const float*)d_in[1];
  const float* w1  = (const float*)d_in[2];
  const float* b1  = (const float*)d_in[3];
  const float* g1  = (const float*)d_in[4];
  const float* be1 = (const float*)d_in[5];
  const float* m1  = (const float*)d_in[6];
  const float* v1  = (const float*)d_in[7];
  const float* w2  = (const float*)d_in[8];
  const float* b2  = (const float*)d_in[9];
  const float* g2  = (const float*)d_in[10];
  const float* be2 = (const float*)d_in[11];
  const float* m2  = (const float*)d_in[12];
  const float* v2  = (const float*)d_in[13];
  const float* w3  = (const float*)d_in[14];
  const float* b3  = (const float*)d_in[15];

  char* ws = (char*)d_ws;
  _Float16* wT1h = (_Float16*)ws;  ws += (size_t)9 * CIN * CIN * 2;
  _Float16* wT2h = (_Float16*)ws;  ws += (size_t)9 * CIN * CIN * 2;
  _Float16* wT3h = (_Float16*)ws;  ws += (size_t)CIN * COUTC * 2;
  _Float16* x0   = (_Float16*)ws;  ws += (size_t)N_IMG * SPH * CIN * 2;
  _Float16* x1h  = (_Float16*)ws;  ws += (size_t)N_IMG * SPH * CIN * 2;
  _Float16* x2h  = (_Float16*)ws;  ws += (size_t)N_IMG * SP * CIN * 2;
  _Float16* feat = (_Float16*)ws;  ws += (size_t)N_IMG * SP * COUTC * 2;
  float*    tmp  = (float*)ws;
  float*    outp = (float*)d_out;

  zero_halo<<<6, 256, 0, stream>>>(x0, x1h);
  prep_w33<<<dim3(256, 2), 256, 0, stream>>>(w1, w2, wT1h, wT2h);
  prep_w11<<<80, 256, 0, stream>>>(w3, wT3h);
  nchw_to_nhwc<<<dim3(44, 4, 6), 256, 0, stream>>>(img, x0);

  conv3x3_mfma<<<dim3(22, 2, 6), 256, 0, stream>>>(x0, wT1h, b1, g1, be1, m1, v1,
                                                   x1h, WW, WW + 1, SPH);
  conv3x3_mfma<<<dim3(22, 2, 6), 256, 0, stream>>>(x1h, wT2h, b2, g2, be2, m2, v2,
                                                   x2h, 88, 0, SP);
  conv1x1_mfma<<<264, 128, 0, stream>>>(x2h, wT3h, b3, feat);

  bev_sample<<<2048, 320, 0, stream>>>(feat, l2i, tmp);
  bev_transpose<<<dim3(512, 3), 256, 0, stream>>>(tmp, outp);
}